// Round 1
// baseline (267.099 us; speedup 1.0000x reference)
//
#include <hip/hip_runtime.h>
#include <stdint.h>

typedef __attribute__((ext_vector_type(4))) float f32x4;
typedef __attribute__((ext_vector_type(8))) short bf16x8;

#define NCH 21
#define NROW 256
#define DIM 4096
#define BM 64
#define BK 64
#define LDS_STRIDE 72  // 64 + 8 bf16 pad: row stride 144B -> only 2-way bank aliasing

__device__ __forceinline__ uint32_t f2bf(float f) {
  union { float f; uint32_t u; } v; v.f = f;
  return (v.u + 0x7fffu + ((v.u >> 16) & 1u)) >> 16;  // RNE, no NaN handling needed
}

// ---------------------------------------------------------------------------
// G[ch] = Tb[ch] * Tb[ch]^T  (Tb = bf16-rounded rows of concat(src,tgt)[:,ch,:])
// 64x64 tile per block, 4 waves each computing 32x32 (2x2 frags of 16x16x32).
// ---------------------------------------------------------------------------
__global__ __launch_bounds__(256) void gram_kernel(
    const float* __restrict__ src, const float* __restrict__ tgt,
    float* __restrict__ G) {
  const int ch = blockIdx.z;
  const int ti = blockIdx.y;
  const int tj = blockIdx.x;
  const int tid = threadIdx.x;
  const int lane = tid & 63;

  __shared__ __attribute__((aligned(16))) ushort As[BM * LDS_STRIDE];
  __shared__ __attribute__((aligned(16))) ushort Bs[BM * LDS_STRIDE];

  f32x4 acc[2][2];
#pragma unroll
  for (int m = 0; m < 2; ++m)
#pragma unroll
    for (int n = 0; n < 2; ++n)
      acc[m][n] = (f32x4){0.f, 0.f, 0.f, 0.f};

  const int wave = tid >> 6;
  const int wrow = (wave >> 1) * 32;
  const int wcol = (wave & 1) * 32;

  // staging: thread handles rows rr+p*16 (p=0..3), float4 at column c4*4
  const int rr = tid >> 4;   // 0..15
  const int c4 = tid & 15;   // 0..15
  const float* aptr[4];
  const float* bptr[4];
#pragma unroll
  for (int p = 0; p < 4; ++p) {
    int ra = ti * BM + rr + p * 16;
    int rb = tj * BM + rr + p * 16;
    aptr[p] = ((ra < 128) ? src + ((size_t)ra * NCH + ch) * DIM
                          : tgt + ((size_t)(ra - 128) * NCH + ch) * DIM) + c4 * 4;
    bptr[p] = ((rb < 128) ? src + ((size_t)rb * NCH + ch) * DIM
                          : tgt + ((size_t)(rb - 128) * NCH + ch) * DIM) + c4 * 4;
  }

  for (int k0 = 0; k0 < DIM; k0 += BK) {
    __syncthreads();  // protect LDS from previous iteration's readers
#pragma unroll
    for (int p = 0; p < 4; ++p) {
      const int row = rr + p * 16;
      f32x4 va = *reinterpret_cast<const f32x4*>(aptr[p] + k0);
      uint2 wa;
      wa.x = f2bf(va.x) | (f2bf(va.y) << 16);
      wa.y = f2bf(va.z) | (f2bf(va.w) << 16);
      *reinterpret_cast<uint2*>(&As[row * LDS_STRIDE + c4 * 4]) = wa;
      f32x4 vb = *reinterpret_cast<const f32x4*>(bptr[p] + k0);
      uint2 wb;
      wb.x = f2bf(vb.x) | (f2bf(vb.y) << 16);
      wb.y = f2bf(vb.z) | (f2bf(vb.w) << 16);
      *reinterpret_cast<uint2*>(&Bs[row * LDS_STRIDE + c4 * 4]) = wb;
    }
    __syncthreads();
#pragma unroll
    for (int kk = 0; kk < 2; ++kk) {
      const int kb = kk * 32 + (lane >> 4) * 8;  // 8 contiguous k per lane
      bf16x8 a[2], b[2];
#pragma unroll
      for (int m = 0; m < 2; ++m)
        a[m] = *reinterpret_cast<const bf16x8*>(
            &As[(wrow + m * 16 + (lane & 15)) * LDS_STRIDE + kb]);
#pragma unroll
      for (int n = 0; n < 2; ++n)
        b[n] = *reinterpret_cast<const bf16x8*>(
            &Bs[(wcol + n * 16 + (lane & 15)) * LDS_STRIDE + kb]);
#pragma unroll
      for (int m = 0; m < 2; ++m)
#pragma unroll
        for (int n = 0; n < 2; ++n)
          acc[m][n] = __builtin_amdgcn_mfma_f32_16x16x32_bf16(a[m], b[n],
                                                              acc[m][n], 0, 0, 0);
    }
  }

  // C/D layout (m89): col = lane&15, row = (lane>>4)*4 + reg
  float* g = G + (size_t)ch * NROW * NROW;
  const int rbase = ti * BM + wrow + ((lane >> 4) << 2);
  const int cbase = tj * BM + wcol + (lane & 15);
#pragma unroll
  for (int m = 0; m < 2; ++m)
#pragma unroll
    for (int n = 0; n < 2; ++n)
#pragma unroll
      for (int j = 0; j < 4; ++j)
        g[(size_t)(rbase + m * 16 + j) * NROW + (cbase + n * 16)] = acc[m][n][j];
}

// ---------------------------------------------------------------------------
__device__ __forceinline__ float block_sum256(float v, float* sm) {
#pragma unroll
  for (int o = 32; o > 0; o >>= 1) v += __shfl_down(v, o, 64);
  const int lane = threadIdx.x & 63;
  const int w = threadIdx.x >> 6;
  if (lane == 0) sm[w] = v;
  __syncthreads();
  float r = 0.f;
  if (threadIdx.x == 0) r = sm[0] + sm[1] + sm[2] + sm[3];
  __syncthreads();  // allow sm reuse
  return r;  // valid on thread 0
}

// per-channel: sum(L2) = 2n*tr(G) - 2*sum(G);  bw = sum(L2)/(n^2-n)/4
__global__ __launch_bounds__(256) void bw_kernel(const float* __restrict__ G,
                                                 float* __restrict__ bwbase) {
  const int ch = blockIdx.x;
  const int tid = threadIdx.x;
  const float* g = G + (size_t)ch * (NROW * NROW);
  float s = 0.f;
  for (int idx = tid; idx < NROW * NROW; idx += 256) s += g[idx];
  float tr = g[tid * (NROW + 1)];
  __shared__ float sm[4];
  float sumG = block_sum256(s, sm);
  float trace = block_sum256(tr, sm);
  if (tid == 0) {
    float sumL2 = 2.f * NROW * trace - 2.f * sumG;
    bwbase[ch] = sumL2 / (float)(NROW * NROW - NROW) / 4.f;
  }
}

// per (channel, 32-row slab): sum_ij s_i s_j sum_a exp(-L2_ij/(bw*2^a))
__global__ __launch_bounds__(256) void mmd_kernel(const float* __restrict__ G,
                                                  const float* __restrict__ bwbase,
                                                  float* __restrict__ partial) {
  const int ch = blockIdx.y;
  const int part = blockIdx.x;  // 0..7
  const int tid = threadIdx.x;
  const float* g = G + (size_t)ch * (NROW * NROW);
  __shared__ float diag[NROW];
  diag[tid] = g[tid * (NROW + 1)];
  __syncthreads();
  const float bw = bwbase[ch];
  float inv[5];
#pragma unroll
  for (int a = 0; a < 5; ++a) inv[a] = -1.f / (bw * (float)(1 << a));
  const float dj = diag[tid];
  float acc = 0.f;
#pragma unroll 4
  for (int it = 0; it < 32; ++it) {
    const int i = part * 32 + it;
    const float L2 = diag[i] + dj - 2.f * g[i * NROW + tid];
    float kv = 0.f;
#pragma unroll
    for (int a = 0; a < 5; ++a) kv += __expf(L2 * inv[a]);
    acc += ((i ^ tid) & 128) ? -kv : kv;
  }
  __shared__ float sm[4];
  float tot = block_sum256(acc, sm);
  if (tid == 0) partial[ch * 8 + part] = tot;
}

__global__ __launch_bounds__(256) void final_kernel(const float* __restrict__ partial,
                                                    float* __restrict__ out) {
  const int tid = threadIdx.x;
  float v = (tid < NCH * 8) ? partial[tid] : 0.f;
  __shared__ float sm[4];
  float tot = block_sum256(v, sm);
  if (tid == 0) out[0] = tot * (1.f / (NCH * 128.f * 128.f));
}

// ---------------------------------------------------------------------------
extern "C" void kernel_launch(void* const* d_in, const int* in_sizes, int n_in,
                              void* d_out, int out_size, void* d_ws, size_t ws_size,
                              hipStream_t stream) {
  const float* src = (const float*)d_in[0];
  const float* tgt = (const float*)d_in[1];
  float* out = (float*)d_out;
  float* G = (float*)d_ws;                               // 21*256*256 f32 = 5.25 MB
  float* bwbase = G + (size_t)NCH * NROW * NROW;         // 21 f32
  float* partial = bwbase + NCH;                         // 168 f32

  gram_kernel<<<dim3(4, 4, NCH), 256, 0, stream>>>(src, tgt, G);
  bw_kernel<<<NCH, 256, 0, stream>>>(G, bwbase);
  mmd_kernel<<<dim3(8, NCH), 256, 0, stream>>>(G, bwbase, partial);
  final_kernel<<<1, 256, 0, stream>>>(partial, out);
}

// Round 5
// 100.929 us; speedup vs baseline: 2.6464x; 2.6464x over previous
//
#include <hip/hip_runtime.h>
#include <hip/hip_bf16.h>
#include <stdint.h>

typedef __attribute__((ext_vector_type(4))) float f32x4;
typedef __attribute__((ext_vector_type(8))) short bf16x8;
typedef __attribute__((ext_vector_type(4))) uint32_t u32x4;

#define NCH 21
#define NROW 256
#define DIM 4096
#define BM 64
#define BK 64
#define LDSS 72  // row stride in ushorts: 144 B (16B-aligned, odd multiple of 16 -> spread bank quads)

__device__ __forceinline__ uint32_t pack_bf2(float x, float y) {
  __hip_bfloat162 h = __float22bfloat162_rn(float2{x, y});  // v_cvt_pk_bf16_f32 (m240: use the cast)
  union { __hip_bfloat162 h; uint32_t u; } c;
  c.h = h;
  return c.u;
}

// ---------------------------------------------------------------------------
// Partial Gram: Gp[ch,ks] = Tb[ch][:, ks*kchunk:(ks+1)*kchunk] * (same)^T
// 64x64 tile / block, 4 waves x (2x2 frags of mfma_f32_16x16x32_bf16).
// Staging: per thread 2 rows x 8 floats -> cvt_pk -> one ds_write_b128 each.
// Prefetch: next K-step's global loads issued before a RAW s_barrier
// (lgkmcnt(0) only) so they stay in flight across the MFMA phase.
// ---------------------------------------------------------------------------
__global__ __launch_bounds__(256) void gram_kernel(
    const float* __restrict__ src, const float* __restrict__ tgt,
    float* __restrict__ Gp, int kshift, int kchunk) {
  const int bz = blockIdx.z;
  const int ch = bz >> kshift;
  const int ks = bz & ((1 << kshift) - 1);
  const int kbase = ks * kchunk;
  const int ti = blockIdx.y;
  const int tj = blockIdx.x;
  const int tid = threadIdx.x;
  const int lane = tid & 63;

  __shared__ __attribute__((aligned(16))) ushort As[BM * LDSS];
  __shared__ __attribute__((aligned(16))) ushort Bs[BM * LDSS];

  f32x4 acc[2][2];
#pragma unroll
  for (int m = 0; m < 2; ++m)
#pragma unroll
    for (int n = 0; n < 2; ++n)
      acc[m][n] = (f32x4){0.f, 0.f, 0.f, 0.f};

  const int wave = tid >> 6;
  const int wrow = (wave >> 1) * 32;
  const int wcol = (wave & 1) * 32;

  // staging geometry: rows r0 and r0+32, 8 floats starting at column c8
  const int r0 = tid >> 3;          // 0..31
  const int c8 = (tid & 7) * 8;     // 0,8,...,56
  const float* ap[2];
  const float* bp[2];
#pragma unroll
  for (int p = 0; p < 2; ++p) {
    int ra = ti * BM + r0 + p * 32;
    int rb = tj * BM + r0 + p * 32;
    ap[p] = ((ra < 128) ? src + ((size_t)ra * NCH + ch) * DIM
                        : tgt + ((size_t)(ra - 128) * NCH + ch) * DIM) + c8;
    bp[p] = ((rb < 128) ? src + ((size_t)rb * NCH + ch) * DIM
                        : tgt + ((size_t)(rb - 128) * NCH + ch) * DIM) + c8;
  }

  f32x4 va[2][2], vb[2][2];
#pragma unroll
  for (int p = 0; p < 2; ++p) {
    va[p][0] = *reinterpret_cast<const f32x4*>(ap[p] + kbase);
    va[p][1] = *reinterpret_cast<const f32x4*>(ap[p] + kbase + 4);
    vb[p][0] = *reinterpret_cast<const f32x4*>(bp[p] + kbase);
    vb[p][1] = *reinterpret_cast<const f32x4*>(bp[p] + kbase + 4);
  }

  const int kend = kbase + kchunk;
  for (int k0 = kbase; k0 < kend; k0 += BK) {
    __syncthreads();  // previous iteration's ds_reads done
#pragma unroll
    for (int p = 0; p < 2; ++p) {
      u32x4 wa, wb;
      wa.x = pack_bf2(va[p][0].x, va[p][0].y);
      wa.y = pack_bf2(va[p][0].z, va[p][0].w);
      wa.z = pack_bf2(va[p][1].x, va[p][1].y);
      wa.w = pack_bf2(va[p][1].z, va[p][1].w);
      *reinterpret_cast<u32x4*>(&As[(r0 + p * 32) * LDSS + c8]) = wa;
      wb.x = pack_bf2(vb[p][0].x, vb[p][0].y);
      wb.y = pack_bf2(vb[p][0].z, vb[p][0].w);
      wb.z = pack_bf2(vb[p][1].x, vb[p][1].y);
      wb.w = pack_bf2(vb[p][1].z, vb[p][1].w);
      *reinterpret_cast<u32x4*>(&Bs[(r0 + p * 32) * LDSS + c8]) = wb;
    }
    // issue next K-step's loads NOW; they fly across the MFMA phase
    if (k0 + BK < kend) {
#pragma unroll
      for (int p = 0; p < 2; ++p) {
        va[p][0] = *reinterpret_cast<const f32x4*>(ap[p] + k0 + BK);
        va[p][1] = *reinterpret_cast<const f32x4*>(ap[p] + k0 + BK + 4);
        vb[p][0] = *reinterpret_cast<const f32x4*>(bp[p] + k0 + BK);
        vb[p][1] = *reinterpret_cast<const f32x4*>(bp[p] + k0 + BK + 4);
      }
    }
    // write-visibility barrier WITHOUT draining vmcnt (T4: never vmcnt(0) here)
    asm volatile("s_waitcnt lgkmcnt(0)" ::: "memory");
    __builtin_amdgcn_s_barrier();
    asm volatile("" ::: "memory");  // keep ds_reads below the barrier

#pragma unroll
    for (int kk = 0; kk < 2; ++kk) {
      const int kb = kk * 32 + (lane >> 4) * 8;
      bf16x8 a[2], b[2];
#pragma unroll
      for (int m = 0; m < 2; ++m)
        a[m] = *reinterpret_cast<const bf16x8*>(
            &As[(wrow + m * 16 + (lane & 15)) * LDSS + kb]);
#pragma unroll
      for (int n = 0; n < 2; ++n)
        b[n] = *reinterpret_cast<const bf16x8*>(
            &Bs[(wcol + n * 16 + (lane & 15)) * LDSS + kb]);
#pragma unroll
      for (int m = 0; m < 2; ++m)
#pragma unroll
        for (int n = 0; n < 2; ++n)
          acc[m][n] = __builtin_amdgcn_mfma_f32_16x16x32_bf16(a[m], b[n],
                                                              acc[m][n], 0, 0, 0);
    }
  }

  // C/D layout (m89): col = lane&15, row = (lane>>4)*4 + reg
  float* g = Gp + (size_t)(ch * (1 << kshift) + ks) * (NROW * NROW);
  const int rbase = ti * BM + wrow + ((lane >> 4) << 2);
  const int cbase = tj * BM + wcol + (lane & 15);
#pragma unroll
  for (int m = 0; m < 2; ++m)
#pragma unroll
    for (int n = 0; n < 2; ++n)
#pragma unroll
      for (int j = 0; j < 4; ++j)
        g[(size_t)(rbase + m * 16 + j) * NROW + (cbase + n * 16)] = acc[m][n][j];
}

// ---------------------------------------------------------------------------
// Gf = sum over K-split partials
__global__ __launch_bounds__(256) void fold_kernel(const f32x4* __restrict__ Gp,
                                                   f32x4* __restrict__ Gf, int P) {
  const int total = NCH * (NROW * NROW / 4);  // 344064 f32x4
  for (int idx = blockIdx.x * 256 + threadIdx.x; idx < total;
       idx += gridDim.x * 256) {
    const int ch = idx >> 14;       // 16384 f32x4 per channel
    const int off = idx & 16383;
    f32x4 s = Gp[(size_t)(ch * P) * 16384 + off];
    for (int p = 1; p < P; ++p) s += Gp[(size_t)(ch * P + p) * 16384 + off];
    Gf[idx] = s;
  }
}

// ---------------------------------------------------------------------------
__device__ __forceinline__ float block_sum256(float v, float* sm) {
#pragma unroll
  for (int o = 32; o > 0; o >>= 1) v += __shfl_down(v, o, 64);
  const int lane = threadIdx.x & 63;
  const int w = threadIdx.x >> 6;
  if (lane == 0) sm[w] = v;
  __syncthreads();
  float r = 0.f;
  if (threadIdx.x == 0) r = sm[0] + sm[1] + sm[2] + sm[3];
  __syncthreads();
  return r;  // valid on thread 0
}

// per (ch, quarter): partial sum(G) and partial trace(G)
__global__ __launch_bounds__(256) void bw_part_kernel(const float* __restrict__ Gf,
                                                      float* __restrict__ sums) {
  const int ch = blockIdx.y;
  const int part = blockIdx.x;  // 0..3
  const float* g = Gf + (size_t)ch * (NROW * NROW);
  const f32x4* gv = reinterpret_cast<const f32x4*>(g + part * 16384);
  float s = 0.f;
  for (int i = threadIdx.x; i < 4096; i += 256) {
    f32x4 v = gv[i];
    s += (v.x + v.y) + (v.z + v.w);
  }
  float tr = (threadIdx.x < 64) ? g[(part * 64 + threadIdx.x) * (NROW + 1)] : 0.f;
  __shared__ float sm[4];
  float sG = block_sum256(s, sm);
  float sT = block_sum256(tr, sm);
  if (threadIdx.x == 0) {
    sums[ch * 8 + part] = sG;
    sums[ch * 8 + 4 + part] = sT;
  }
}

// per (ch, 32-row slab): sum_ij s_i s_j sum_a exp(-L2_ij/(bw*2^a))
__global__ __launch_bounds__(256) void mmd_kernel(const float* __restrict__ Gf,
                                                  const float* __restrict__ sums,
                                                  float* __restrict__ partial) {
  const int ch = blockIdx.y;
  const int part = blockIdx.x;  // 0..7
  const int tid = threadIdx.x;
  const float* g = Gf + (size_t)ch * (NROW * NROW);
  // reconstruct bandwidth from the 8 per-channel scalars (all threads, broadcast)
  const float* sc = sums + ch * 8;
  float sumG = (sc[0] + sc[1]) + (sc[2] + sc[3]);
  float tr = (sc[4] + sc[5]) + (sc[6] + sc[7]);
  float sumL2 = 2.f * NROW * tr - 2.f * sumG;
  float bw = sumL2 / (float)(NROW * NROW - NROW) * 0.25f;

  __shared__ float diag[NROW];
  diag[tid] = g[tid * (NROW + 1)];
  __syncthreads();
  float inv[5];
#pragma unroll
  for (int a = 0; a < 5; ++a) inv[a] = -1.f / (bw * (float)(1 << a));
  const float dj = diag[tid];
  float acc = 0.f;
#pragma unroll 4
  for (int it = 0; it < 32; ++it) {
    const int i = part * 32 + it;
    const float L2 = diag[i] + dj - 2.f * g[i * NROW + tid];
    float kv = 0.f;
#pragma unroll
    for (int a = 0; a < 5; ++a) kv += __expf(L2 * inv[a]);
    acc += ((i ^ tid) & 128) ? -kv : kv;
  }
  __shared__ float sm[4];
  float tot = block_sum256(acc, sm);
  if (tid == 0) partial[ch * 8 + part] = tot;
}

__global__ __launch_bounds__(256) void final_kernel(const float* __restrict__ partial,
                                                    float* __restrict__ out) {
  const int tid = threadIdx.x;
  float v = (tid < NCH * 8) ? partial[tid] : 0.f;
  __shared__ float sm[4];
  float tot = block_sum256(v, sm);
  if (tid == 0) out[0] = tot * (1.f / (NCH * 128.f * 128.f));
}

// ---------------------------------------------------------------------------
extern "C" void kernel_launch(void* const* d_in, const int* in_sizes, int n_in,
                              void* d_out, int out_size, void* d_ws, size_t ws_size,
                              hipStream_t stream) {
  const float* src = (const float*)d_in[0];
  const float* tgt = (const float*)d_in[1];
  float* out = (float*)d_out;
  const size_t GSZ = (size_t)NROW * NROW;  // 65536

  // pick K-split by available workspace: P slices + 1 folded + scalars
  int kshift = 0;
  if (ws_size >= (NCH * 5 * GSZ + 64) * sizeof(float)) kshift = 2;
  else if (ws_size >= (NCH * 3 * GSZ + 64) * sizeof(float)) kshift = 1;
  const int P = 1 << kshift;

  float* Gp = (float*)d_ws;
  float* Gf = (P > 1) ? Gp + (size_t)NCH * P * GSZ : Gp;  // P==1: alias, skip fold
  float* sums = Gf + (size_t)NCH * GSZ;
  float* partial = sums + NCH * 8;

  gram_kernel<<<dim3(4, 4, NCH * P), 256, 0, stream>>>(src, tgt, Gp, kshift,
                                                       DIM >> kshift);
  if (P > 1)
    fold_kernel<<<dim3(1344), 256, 0, stream>>>((const f32x4*)Gp, (f32x4*)Gf, P);
  bw_part_kernel<<<dim3(4, NCH), 256, 0, stream>>>(Gf, sums);
  mmd_kernel<<<dim3(8, NCH), 256, 0, stream>>>(Gf, sums, partial);
  final_kernel<<<1, 256, 0, stream>>>(partial, out);
}